// Round 1
// baseline (7676.991 us; speedup 1.0000x reference)
//
#include <hip/hip_runtime.h>
#include <cstdint>
#include <climits>
#include <cstddef>

#define DD    1024
#define DFFN  4096
#define NVOC  32000
#define NTT   1024
#define NTOKS 2048

typedef float  f32x4   __attribute__((ext_vector_type(4)));
typedef __bf16 bf16x8  __attribute__((ext_vector_type(8)));
typedef short  short8  __attribute__((ext_vector_type(8)));
typedef short  short4v __attribute__((ext_vector_type(4)));

__device__ __forceinline__ float sigf(float x) { return 1.f / (1.f + expf(-x)); }

// ---------- block reduce (256 threads) ----------
__device__ __forceinline__ float blkredsum(float v, float* sb) {
  for (int o = 32; o; o >>= 1) v += __shfl_down(v, o);
  __syncthreads();
  if ((threadIdx.x & 63) == 0) sb[threadIdx.x >> 6] = v;
  __syncthreads();
  return sb[0] + sb[1] + sb[2] + sb[3];
}

// =================== LayerNorm kernels ===================
__global__ __launch_bounds__(256) void k_embed_ln(const int* __restrict__ idx,
    const float* __restrict__ emb, const float* __restrict__ w, const float* __restrict__ b,
    float* __restrict__ out) {
  __shared__ float sb[8];
  int tok = blockIdx.x;
  int row = idx[tok];
  const float* xr = emb + (size_t)row * DD;
  int t = threadIdx.x;
  f32x4 x = *(const f32x4*)(xr + t * 4);
  float s = x[0] + x[1] + x[2] + x[3];
  float q = x[0]*x[0] + x[1]*x[1] + x[2]*x[2] + x[3]*x[3];
  for (int o = 32; o; o >>= 1) { s += __shfl_down(s, o); q += __shfl_down(q, o); }
  if ((t & 63) == 0) { sb[t >> 6] = s; sb[4 + (t >> 6)] = q; }
  __syncthreads();
  s = sb[0] + sb[1] + sb[2] + sb[3];
  q = sb[4] + sb[5] + sb[6] + sb[7];
  float mean = s * (1.f / DD);
  float var  = q * (1.f / DD) - mean * mean;
  float rstd = rsqrtf(var + 1e-5f);
  f32x4 wv = *(const f32x4*)(w + t * 4);
  f32x4 bv = *(const f32x4*)(b + t * 4);
  f32x4 o4;
  #pragma unroll
  for (int e = 0; e < 4; ++e) o4[e] = (x[e] - mean) * rstd * wv[e] + bv[e];
  *(f32x4*)(out + (size_t)tok * DD + t * 4) = o4;
}

__global__ __launch_bounds__(256) void k_ln(const float* __restrict__ in,
    const float* __restrict__ w, const float* __restrict__ b, float* __restrict__ out) {
  __shared__ float sb[8];
  int tok = blockIdx.x;
  const float* xr = in + (size_t)tok * DD;
  int t = threadIdx.x;
  f32x4 x = *(const f32x4*)(xr + t * 4);
  float s = x[0] + x[1] + x[2] + x[3];
  float q = x[0]*x[0] + x[1]*x[1] + x[2]*x[2] + x[3]*x[3];
  for (int o = 32; o; o >>= 1) { s += __shfl_down(s, o); q += __shfl_down(q, o); }
  if ((t & 63) == 0) { sb[t >> 6] = s; sb[4 + (t >> 6)] = q; }
  __syncthreads();
  s = sb[0] + sb[1] + sb[2] + sb[3];
  q = sb[4] + sb[5] + sb[6] + sb[7];
  float mean = s * (1.f / DD);
  float var  = q * (1.f / DD) - mean * mean;
  float rstd = rsqrtf(var + 1e-5f);
  f32x4 wv = *(const f32x4*)(w + t * 4);
  f32x4 bv = *(const f32x4*)(b + t * 4);
  f32x4 o4;
  #pragma unroll
  for (int e = 0; e < 4; ++e) o4[e] = (x[e] - mean) * rstd * wv[e] + bv[e];
  *(f32x4*)(out + (size_t)tok * DD + t * 4) = o4;
}

// =================== GEMM: C[M,N] = A[M,K] @ B[N,K]^T (bf16x2 split MFMA) ===================
// LDS fragment-major layout: per 16-row block: 4 k-chunks of 8, chunk stride 136 (pad),
// block stride 544.  Lane l reads 8 contiguous shorts at (l&15)*8 + (l>>4)*136 -> linear, CF.
#define KCH   136
#define BLKS  544
#define TILESH 4352

template<int RESID>
__global__ __launch_bounds__(256) void gemm_bt(
    const float* __restrict__ A, int lda,
    const float* __restrict__ B0, const float* __restrict__ B1, const float* __restrict__ B2,
    int ns1, int ns2,
    float* __restrict__ C, int ldc,
    const float* __restrict__ R,
    int Ntiles, int K)
{
  __shared__ short Ah[TILESH], Al[TILESH], Bh[TILESH], Bl[TILESH];
  // bijective XCD swizzle
  int nwg = gridDim.x, g = blockIdx.x;
  int qq = nwg >> 3, rr = nwg & 7;
  int xcd = g & 7, lin = g >> 3;
  int wg = (xcd < rr ? xcd * (qq + 1) : rr * (qq + 1) + (xcd - rr) * qq) + lin;
  int nt = wg % Ntiles, mt = wg / Ntiles;
  int m0 = mt * 128, n0 = nt * 128;
  const float* Bp; int nb0;
  if (n0 < ns1)      { Bp = B0; nb0 = n0; }
  else if (n0 < ns2) { Bp = B1; nb0 = n0 - ns1; }
  else               { Bp = B2; nb0 = n0 - ns2; }

  const int t = threadIdx.x;
  const int srow = t >> 3;          // 0..31, +s*32
  const int scol = (t & 7) << 2;    // 0,4,...,28
  const float* Abase = A  + (size_t)m0  * lda + scol;
  const float* Bbase = Bp + (size_t)nb0 * K   + scol;

  f32x4 ra[4], rb[4];
  auto loadT = [&](int kt) {
    size_t ko = (size_t)kt * 32;
    #pragma unroll
    for (int s = 0; s < 4; ++s) {
      int row = s * 32 + srow;
      ra[s] = *(const f32x4*)(Abase + (size_t)row * lda + ko);
      rb[s] = *(const f32x4*)(Bbase + (size_t)row * K   + ko);
    }
  };
  auto conv4 = [](f32x4 v, short4v& hi, short4v& lo) {
    #pragma unroll
    for (int e = 0; e < 4; ++e) {
      float x = v[e];
      unsigned u  = __builtin_bit_cast(unsigned, x);
      unsigned hf = u & 0xFFFF0000u;
      float rem   = x - __builtin_bit_cast(float, hf);
      unsigned ur = __builtin_bit_cast(unsigned, rem);
      hi[e] = (short)(u >> 16);
      lo[e] = (short)((ur + 0x7FFFu + ((ur >> 16) & 1u)) >> 16);
    }
  };
  auto storeT = [&]() {
    #pragma unroll
    for (int s = 0; s < 4; ++s) {
      int row = s * 32 + srow;
      int idx = (row >> 4) * BLKS + (scol >> 3) * KCH + (row & 15) * 8 + (scol & 7);
      short4v h4, l4;
      conv4(ra[s], h4, l4);
      *(short4v*)&Ah[idx] = h4; *(short4v*)&Al[idx] = l4;
      conv4(rb[s], h4, l4);
      *(short4v*)&Bh[idx] = h4; *(short4v*)&Bl[idx] = l4;
    }
  };

  const int lane = t & 63, wid = t >> 6;
  const int wr = wid >> 1, wc = wid & 1;
  const int fro  = (lane & 15) * 8 + (lane >> 4) * KCH;
  const int aoff = (wr * 4) * BLKS + fro;
  const int boff = (wc * 4) * BLKS + fro;

  f32x4 acc[4][4] = {};
  int KT = K >> 5;
  loadT(0); storeT();
  __syncthreads();
  for (int kt = 0; kt < KT; ++kt) {
    bf16x8 ah[4], al[4], bh[4], bl[4];
    #pragma unroll
    for (int i = 0; i < 4; ++i) {
      ah[i] = __builtin_bit_cast(bf16x8, *(const short8*)&Ah[aoff + i * BLKS]);
      al[i] = __builtin_bit_cast(bf16x8, *(const short8*)&Al[aoff + i * BLKS]);
      bh[i] = __builtin_bit_cast(bf16x8, *(const short8*)&Bh[boff + i * BLKS]);
      bl[i] = __builtin_bit_cast(bf16x8, *(const short8*)&Bl[boff + i * BLKS]);
    }
    bool more = (kt + 1 < KT);
    if (more) loadT(kt + 1);
    #pragma unroll
    for (int i = 0; i < 4; ++i)
      #pragma unroll
      for (int j = 0; j < 4; ++j)
        acc[i][j] = __builtin_amdgcn_mfma_f32_16x16x32_bf16(ah[i], bh[j], acc[i][j], 0, 0, 0);
    #pragma unroll
    for (int i = 0; i < 4; ++i)
      #pragma unroll
      for (int j = 0; j < 4; ++j)
        acc[i][j] = __builtin_amdgcn_mfma_f32_16x16x32_bf16(ah[i], bl[j], acc[i][j], 0, 0, 0);
    #pragma unroll
    for (int i = 0; i < 4; ++i)
      #pragma unroll
      for (int j = 0; j < 4; ++j)
        acc[i][j] = __builtin_amdgcn_mfma_f32_16x16x32_bf16(al[i], bh[j], acc[i][j], 0, 0, 0);
    if (more) { __syncthreads(); storeT(); __syncthreads(); }
  }
  // epilogue: D row=(l>>4)*4+e, col=l&15
  #pragma unroll
  for (int i = 0; i < 4; ++i) {
    int rbase = m0 + wr * 64 + i * 16 + ((lane >> 4) << 2);
    #pragma unroll
    for (int j = 0; j < 4; ++j) {
      int cc = n0 + wc * 64 + j * 16 + (lane & 15);
      f32x4 v = acc[i][j];
      #pragma unroll
      for (int e = 0; e < 4; ++e) {
        size_t off = (size_t)(rbase + e) * ldc + cc;
        float val = v[e];
        if (RESID) val += R[off];
        C[off] = val;
      }
    }
  }
}

// =================== decay-cumsum scan (3 passes) ===================
__global__ __launch_bounds__(256) void k_scan1(const float* __restrict__ rkv, float* __restrict__ y,
      float* __restrict__ chunks, const float* __restrict__ dec) {
  int tid = blockIdx.x * 256 + threadIdx.x;   // 32768
  int q = tid >> 11, c = tid & 2047;
  int b = c >> 10, d = c & 1023;
  float dv = sigf(dec[d]);
  float ldec = logf(fmaxf(dv, 1e-7f));
  const float* kp = rkv + (size_t)(b * NTT) * 3072 + DD + d;
  const float* vp = kp + DD;
  float s = 0.f;
  int t0 = q * 64;
  for (int i = 0; i < 64; ++i) {
    int tt = t0 + i;
    float kk = kp[(size_t)tt * 3072];
    float vv = vp[(size_t)tt * 3072];
    float sc = expf((float)tt * ldec);
    float yv = (kk * vv) / fmaxf(sc, 1e-10f);
    y[(size_t)(b * NTT + tt) * DD + d] = yv;
    s += yv;
  }
  chunks[c * 16 + q] = s;
}

__global__ void k_scan2(float* __restrict__ chunks) {
  int c = blockIdx.x * 256 + threadIdx.x;   // 2048
  float run = 0.f;
  #pragma unroll
  for (int q = 0; q < 16; ++q) {
    float v = chunks[c * 16 + q];
    chunks[c * 16 + q] = run;
    run += v;
  }
}

__global__ __launch_bounds__(256) void k_scan3(const float* __restrict__ rkv, const float* __restrict__ y,
      const float* __restrict__ chunks, float* __restrict__ out,
      const float* __restrict__ dec, double* __restrict__ gst) {
  __shared__ float sb[8];
  int tid = blockIdx.x * 256 + threadIdx.x;
  int q = tid >> 11, c = tid & 2047;
  int b = c >> 10, d = c & 1023;
  float dv = sigf(dec[d]);
  float ldec = logf(fmaxf(dv, 1e-7f));
  const float* rp = rkv + (size_t)(b * NTT) * 3072 + d;
  float cum = chunks[c * 16 + q];
  float ls = 0.f, lq = 0.f;
  int t0 = q * 64;
  for (int i = 0; i < 64; ++i) {
    int tt = t0 + i;
    float yv = y[(size_t)(b * NTT + tt) * DD + d];
    cum += yv;
    float sc = expf((float)tt * ldec);
    float r = sigf(rp[(size_t)tt * 3072]);
    float o = r * (cum * sc);
    out[(size_t)(b * NTT + tt) * DD + d] = o;
    ls += o; lq += o * o;
  }
  for (int o2 = 32; o2; o2 >>= 1) { ls += __shfl_down(ls, o2); lq += __shfl_down(lq, o2); }
  int lane = threadIdx.x & 63, wid = threadIdx.x >> 6;
  if (!lane) { sb[wid] = ls; sb[4 + wid] = lq; }
  __syncthreads();
  if (threadIdx.x == 0) {
    atomicAdd(&gst[b * 2 + 0], (double)(sb[0] + sb[1] + sb[2] + sb[3]));
    atomicAdd(&gst[b * 2 + 1], (double)(sb[4] + sb[5] + sb[6] + sb[7]));
  }
}

__global__ __launch_bounds__(256) void k_gnorm(const float* __restrict__ in, float* __restrict__ out,
      const double* __restrict__ gst, const float* __restrict__ gw, const float* __restrict__ gb) {
  int i4 = blockIdx.x * 256 + threadIdx.x;   // 524288
  size_t f = (size_t)i4 * 4;
  int b = (int)(f >> 20);
  int d = (int)(f & 1023);
  double cnt = 1048576.0;
  double mu = gst[b * 2 + 0] / cnt;
  double va = gst[b * 2 + 1] / cnt - mu * mu;
  float m = (float)mu;
  float rstd = rsqrtf((float)va + 1e-5f);
  f32x4 x  = *(const f32x4*)(in + f);
  f32x4 w4 = *(const f32x4*)(gw + d);
  f32x4 b4 = *(const f32x4*)(gb + d);
  f32x4 o4;
  #pragma unroll
  for (int e = 0; e < 4; ++e) o4[e] = (x[e] - m) * rstd * w4[e] + b4[e];
  *(f32x4*)(out + f) = o4;
}

__global__ __launch_bounds__(256) void k_silu(float* __restrict__ uv) {
  int i4 = blockIdx.x * 256 + threadIdx.x;   // 2,097,152
  size_t f = (size_t)i4 * 4;
  size_t row = f >> 12, col = f & 4095;
  float* up = uv + row * 8192 + col;
  const float* vp = uv + row * 8192 + 4096 + col;
  f32x4 u = *(const f32x4*)up;
  f32x4 v = *(const f32x4*)vp;
  f32x4 o;
  #pragma unroll
  for (int e = 0; e < 4; ++e) o[e] = u[e] * sigf(u[e]) * v[e];
  *(f32x4*)up = o;
}

// =================== per-token head reduction (lse/ce/argmax/entropy) ===================
__global__ __launch_bounds__(256) void k_headred(const float* __restrict__ lg, const int* __restrict__ tgt,
      int* __restrict__ pred, float* __restrict__ entout, double* __restrict__ cesum) {
  __shared__ float sm[256], ss[256], sl[256], sav[256];
  __shared__ int sai[256];
  __shared__ float stv;
  int tok = blockIdx.x;
  const float* L = lg + (size_t)tok * NVOC;
  int tg = tgt[tok];
  int t = threadIdx.x;
  float m = -3.4e38f, s1 = 0.f, slg = 0.f, amv = -3.4e38f;
  int ami = 0x7FFFFFFF;
  for (int v = t; v < NVOC; v += 256) {
    float x = L[v];
    if (x > amv) { amv = x; ami = v; }
    if (x > m) {
      float e = expf(m - x);
      s1 = s1 * e + 1.f; slg = slg * e + x; m = x;
    } else {
      float e = expf(x - m);
      s1 += e; slg += e * x;
    }
    if (v == tg) stv = x;
  }
  sm[t] = m; ss[t] = s1; sl[t] = slg; sav[t] = amv; sai[t] = ami;
  __syncthreads();
  for (int o = 128; o; o >>= 1) {
    if (t < o) {
      float m2 = sm[t + o], mn = fmaxf(sm[t], m2);
      float e1 = expf(sm[t] - mn), e2 = expf(m2 - mn);
      ss[t] = ss[t] * e1 + ss[t + o] * e2;
      sl[t] = sl[t] * e1 + sl[t + o] * e2;
      sm[t] = mn;
      float av2 = sav[t + o]; int ai2 = sai[t + o];
      if (av2 > sav[t] || (av2 == sav[t] && ai2 < sai[t])) { sav[t] = av2; sai[t] = ai2; }
    }
    __syncthreads();
  }
  if (t == 0) {
    float lse = sm[0] + logf(ss[0]);
    pred[tok] = sai[0];
    if (entout) entout[tok] = lse - sl[0] / ss[0];
    atomicAdd(cesum, (double)(stv - lse));
  }
}

// =================== gate path ===================
__global__ __launch_bounds__(256) void k_hemean(const float* __restrict__ h, float* __restrict__ hm) {
  int tid = blockIdx.x * 256 + threadIdx.x;  // 16384
  int tc = tid >> 11, c = tid & 2047;
  int b = c >> 10, d = c & 1023;
  const float* p = h + (size_t)(b * NTT) * DD + d;
  float s = 0.f;
  int tbase = tc * 128;
  for (int i = 0; i < 128; ++i) s += p[(size_t)(tbase + i) * DD];
  atomicAdd(&hm[c], s * (1.f / NTT));
}

__global__ __launch_bounds__(256) void k_gate1(const float* __restrict__ hm, const float* __restrict__ w1,
      const float* __restrict__ b1, float* __restrict__ g1) {
  __shared__ float sb[4];
  int b = blockIdx.x >> 6, o = blockIdx.x & 63;
  int t = threadIdx.x;
  f32x4 h4 = *(const f32x4*)(hm + (size_t)b * DD + t * 4);
  f32x4 w4 = *(const f32x4*)(w1 + (size_t)o * DD + t * 4);
  float s = h4[0]*w4[0] + h4[1]*w4[1] + h4[2]*w4[2] + h4[3]*w4[3];
  s = blkredsum(s, sb);
  if (t == 0) g1[b * 64 + o] = fmaxf(s + b1[o], 0.f);
}

__global__ void k_gate2(const float* __restrict__ g1, const float* __restrict__ w2,
      const float* __restrict__ b2, float* __restrict__ conf) {
  int b = blockIdx.x; int t = threadIdx.x;
  float v = g1[b * 64 + t] * w2[t];
  for (int o = 32; o; o >>= 1) v += __shfl_down(v, o);
  if (t == 0) conf[b] = sigf(v + b2[0]);
}

// =================== final loss assembly ===================
__global__ __launch_bounds__(256) void k_loss(const double* __restrict__ cesum, const float* __restrict__ confb,
      const int* __restrict__ ep0, const int* __restrict__ ep1, const int* __restrict__ fpred,
      const float* __restrict__ ent0, const float* __restrict__ ent1, float* __restrict__ lossout) {
  __shared__ float sb[4];
  int t = threadIdx.x;
  float a00 = 0, a01 = 0, a10 = 0, a11 = 0, oc0 = 0, oc1 = 0;
  const float inv_me = 1.f / 10.373491181781864f;   // 1/log(32000)
  for (int tok = t; tok < NTOKS; tok += 256) {
    int fp = fpred[tok];
    int bb = tok >> 10;
    float m0 = (ep0[tok] == fp) ? 1.f : 0.f;
    float m1 = (ep1[tok] == fp) ? 1.f : 0.f;
    if (bb) { a01 += m0; a11 += m1; } else { a00 += m0; a10 += m1; }
    oc0 += (1.f - ent0[tok] * inv_me) * (1.f - m0);
    oc1 += (1.f - ent1[tok] * inv_me) * (1.f - m1);
  }
  a00 = blkredsum(a00, sb); a01 = blkredsum(a01, sb);
  a10 = blkredsum(a10, sb); a11 = blkredsum(a11, sb);
  oc0 = blkredsum(oc0, sb); oc1 = blkredsum(oc1, sb);
  if (t == 0) {
    float Wj[2] = {0.3f, 0.5f};
    double loss = -cesum[0] / (double)NTOKS;   // final CE * 1.0
    float ag[2][2] = {{a00, a01}, {a10, a11}};
    float oc[2] = {oc0, oc1};
    for (int j = 0; j < 2; ++j) {
      loss += (double)Wj[j] * (-cesum[1 + j] / (double)NTOKS);
      float bce = 0.f;
      for (int bb = 0; bb < 2; ++bb) {
        float agree = ag[j][bb] * (1.f / NTT);
        float c = confb[j * 2 + bb];
        c = fminf(fmaxf(c, 1e-7f), 1.f - 1e-7f);
        bce += -(agree * logf(c) + (1.f - agree) * logf(1.f - c));
      }
      loss += 0.5 * (double)(bce * 0.5f);
      loss += 0.1 * (double)(oc[j] * (1.f / NTOKS));
    }
    lossout[0] = (float)loss;
  }
}

// =================== host ===================
extern "C" void kernel_launch(void* const* d_in, const int* in_sizes, int n_in,
                              void* d_out, int out_size, void* d_ws, size_t ws_size,
                              hipStream_t stream) {
  (void)in_sizes; (void)n_in; (void)out_size; (void)ws_size;
  const int*   idx      = (const int*)d_in[0];
  const int*   targets  = (const int*)d_in[1];
  const float* embed    = (const float*)d_in[2];
  const float* ln_in_w  = (const float*)d_in[3];
  const float* ln_in_b  = (const float*)d_in[4];
  const float* Wr       = (const float*)d_in[5];
  const float* Wk       = (const float*)d_in[6];
  const float* Wv       = (const float*)d_in[7];
  const float* Wo_tm    = (const float*)d_in[8];
  const float* decay    = (const float*)d_in[9];
  const float* gn_w     = (const float*)d_in[10];
  const float* gn_b     = (const float*)d_in[11];
  const float* ln1_w    = (const float*)d_in[12];
  const float* ln1_b    = (const float*)d_in[13];
  const float* ln2_w    = (const float*)d_in[14];
  const float* ln2_b    = (const float*)d_in[15];
  const float* W1       = (const float*)d_in[16];
  const float* W2       = (const float*)d_in[17];
  const float* Wo_cm    = (const float*)d_in[18];
  const float* ln_out_w = (const float*)d_in[19];
  const float* ln_out_b = (const float*)d_in[20];
  const float* exit_ln_w= (const float*)d_in[21];
  const float* exit_ln_b= (const float*)d_in[22];
  const float* exit_head= (const float*)d_in[23];
  const float* gate_w1  = (const float*)d_in[24];
  const float* gate_b1  = (const float*)d_in[25];
  const float* gate_w2  = (const float*)d_in[26];
  const float* gate_b2  = (const float*)d_in[27];

  float* ws   = (float*)d_ws;
  float* x    = ws;                   // 2,097,152
  float* h    = ws + 2097152;         // 2,097,152
  float* rkv  = ws + 4194304;         // 6,291,456
  float* ybuf = ws + 10485760;        // 2,097,152
  float* obuf = ws + 12582912;        // 2,097,152
  float* uv   = ws + 14680064;        // 16,777,216
  float* S    = ws + 31457280;        // smalls
  double* gnstat = (double*)S;              // 48 dbl (12 layers x [b][sum,sq])
  double* cesum  = (double*)(S + 96);       // 3 dbl: final, exit0, exit1
  float* hemean  = S + 104;                 // [2][2048]
  float* chunks  = S + 4224;                // 32768
  int*   ep0     = (int*)(S + 36992);
  int*   ep1     = (int*)(S + 39040);
  int*   fpred   = (int*)(S + 41088);
  float* ent0    = S + 43136;
  float* ent1    = S + 45184;
  float* g1buf   = S + 47232;               // [2][64]
  float* confb   = S + 47360;               // [2][2]
  float* logits  = (float*)d_out;           // exit logits staged here, final logits last
  float* lossp   = (float*)d_out + (size_t)NTOKS * NVOC;

  const int BIG = 0x7FFFFFFF;
  hipMemsetAsync(S, 0, 16896, stream);   // zero gnstat + cesum + hemean

  k_embed_ln<<<NTOKS, 256, 0, stream>>>(idx, embed, ln_in_w, ln_in_b, x);

  for (int i = 0; i < 12; ++i) {
    size_t oD  = (size_t)i * DD;
    size_t oDD = (size_t)i * DD * DD;
    size_t oDF = (size_t)i * (size_t)DFFN * DD;
    // --- TimeMix ---
    k_ln<<<NTOKS, 256, 0, stream>>>(x, ln1_w + oD, ln1_b + oD, h);
    gemm_bt<0><<<16 * 24, 256, 0, stream>>>(h, DD, Wr + oDD, Wk + oDD, Wv + oDD,
                                            1024, 2048, rkv, 3072, nullptr, 24, DD);
    k_scan1<<<128, 256, 0, stream>>>(rkv, ybuf, chunks, decay + oD);
    k_scan2<<<8, 256, 0, stream>>>(chunks);
    k_scan3<<<128, 256, 0, stream>>>(rkv, ybuf, chunks, obuf, decay + oD, gnstat + (size_t)i * 4);
    k_gnorm<<<2048, 256, 0, stream>>>(obuf, h, gnstat + (size_t)i * 4, gn_w + oD, gn_b + oD);
    gemm_bt<1><<<16 * 8, 256, 0, stream>>>(h, DD, Wo_tm + oDD, nullptr, nullptr,
                                           BIG, BIG, x, DD, x, 8, DD);
    // --- ChannelMix ---
    k_ln<<<NTOKS, 256, 0, stream>>>(x, ln2_w + oD, ln2_b + oD, h);
    gemm_bt<0><<<16 * 64, 256, 0, stream>>>(h, DD, W1 + oDF, W2 + oDF, nullptr,
                                            4096, BIG, uv, 8192, nullptr, 64, DD);
    k_silu<<<8192, 256, 0, stream>>>(uv);
    gemm_bt<1><<<16 * 8, 256, 0, stream>>>(uv, 8192, Wo_cm + oDF, nullptr, nullptr,
                                           BIG, BIG, x, DD, x, 8, DFFN);
    // --- early exits ---
    if (i == 3 || i == 7) {
      int j = (i == 3) ? 0 : 1;
      k_ln<<<NTOKS, 256, 0, stream>>>(x, exit_ln_w + (size_t)j * DD, exit_ln_b + (size_t)j * DD, h);
      gemm_bt<0><<<16 * 250, 256, 0, stream>>>(h, DD, exit_head + (size_t)j * NVOC * DD,
                                               nullptr, nullptr, BIG, BIG,
                                               logits, NVOC, nullptr, 250, DD);
      k_headred<<<NTOKS, 256, 0, stream>>>(logits, targets, j ? ep1 : ep0, j ? ent1 : ent0, cesum + 1 + j);
      k_hemean<<<64, 256, 0, stream>>>(h, hemean + (size_t)j * 2048);
      k_gate1<<<128, 256, 0, stream>>>(hemean + (size_t)j * 2048, gate_w1 + (size_t)j * 64 * DD,
                                       gate_b1 + (size_t)j * 64, g1buf + (size_t)j * 64);
      k_gate2<<<2, 64, 0, stream>>>(g1buf + (size_t)j * 64, gate_w2 + (size_t)j * 64,
                                    gate_b2 + j, confb + (size_t)j * 2);
    }
  }
  // --- final head + loss ---
  k_ln<<<NTOKS, 256, 0, stream>>>(x, ln_out_w, ln_out_b, h);
  gemm_bt<0><<<16 * 250, 256, 0, stream>>>(h, DD, embed, nullptr, nullptr, BIG, BIG,
                                           logits, NVOC, nullptr, 250, DD);
  k_headred<<<NTOKS, 256, 0, stream>>>(logits, targets, fpred, nullptr, cesum);
  k_loss<<<1, 256, 0, stream>>>(cesum, confb, ep0, ep1, fpred, ent0, ent1, lossp);
}